// Round 11
// baseline (82.374 us; speedup 1.0000x reference)
//
#include <hip/hip_runtime.h>

#define CINC 64
#define COUT 64
#define HH 32
#define WW 32
#define BB 16
#define NSPLIT 4
#define CPS 16            // cin per split

typedef __attribute__((ext_vector_type(8))) short short8;
typedef __attribute__((ext_vector_type(4))) float floatx4;

__device__ __forceinline__ unsigned short f2bf(float f) {
    union { float f; unsigned int u; } c; c.f = f;
    unsigned int r = (c.u + 0x7FFFu + ((c.u >> 16) & 1u)) >> 16;
    return (unsigned short)r;
}

// W3 layout (COALESCED, round-6 verified):
// [split(4)][ts(36)][half(2)][nt(2)][q(4)][l15(16)][e(8)] bf16.
// Per (split,ts,half,nt) fragment, lane (q,l15) reads shorts [lane*8..lane*8+7]
// -> one fully-contiguous 1 KB wave read. ts = tap*4 + s.
__global__ __launch_bounds__(256) void wt_kernel(const float* __restrict__ sw,
                                                 const float* __restrict__ sc,
                                                 short* __restrict__ W3) {
    int idx = blockIdx.x * blockDim.x + threadIdx.x;
    const int total = NSPLIT * 36 * 2 * 2 * 4 * 16 * 8;   // 294,912
    if (idx >= total) return;
    int e    = idx & 7;
    int l15  = (idx >> 3) & 15;
    int q    = (idx >> 7) & 3;
    int nt   = (idx >> 9) & 1;
    int half = (idx >> 10) & 1;
    int tsid = idx >> 11;            // 0..143 = split*36 + ts
    int ts   = tsid % 36;
    int split = tsid / 36;
    int s = ts & 3, tap = ts >> 2;
    int oc = half * 32 + nt * 16 + l15;
    int cin = split * CPS + s * 4 + q;
    int g = e;
    int kh = tap / 3, kw = tap % 3;
    float w = sw[(((oc * CINC + cin) * 8 + g) * 3 + kh) * 3 + kw] * sc[oc * CINC + cin];
    W3[idx] = (short)f2bf(w);
}

// Counted vmcnt wait tied to the regs about to be consumed (true data dep).
#define VM_WAIT(N, a, b) asm volatile("s_waitcnt vmcnt(" #N ")" : "+v"(a), "+v"(b))
// Issue one step's two B-fragment loads (nt=0 at p, nt=1 at p+1024 B).
#define B_ISSUE(a, b, p)                                            \
    asm volatile("global_load_dwordx4 %0, %2, off\n\t"              \
                 "global_load_dwordx4 %1, %2, off offset:1024"      \
                 : "=&v"(a), "=&v"(b) : "v"(p))

// Fused bases + implicit-GEMM conv with in-block cin-split reduction.
// TCP-THROUGHPUT RESTRUCTURE (this round): the per-CU L1/TCP services every
// B-load at ~64 B/clk; 16 waves x 2 KB/step = 32 KB/CU-step = ~500 cyc,
// matching the measured 458 cyc/CU-step and explaining 5 nulls across the
// latency/TLP/phase axes (service throughput, not timing, binds). The old
// rowl-pair waves loaded IDENTICAL B fragments (2x duplication through TCP).
// New: 8 waves/block (512 thr), wave = (split = w&3, oc-half = w>>2); each
// wave computes BOTH rows x BOTH x-halves (4 A-frags, 8 MFMAs/step,
// acc[row][xh][nt]) -> 16 KB of B per CU-step for the same 64 MFMAs: 2x less
// TCP service per unit work, zero duplicate streams.
// B: depth-4 pinned pipeline, counted vmcnt, copy-free consume-then-reissue.
__global__ __launch_bounds__(512, 2) void conv_kernel(const float* __restrict__ xin,
                                                      const short* __restrict__ W3,
                                                      float* __restrict__ out) {
    __shared__ __align__(16) char smem[139264];
    short* A = (short*)smem;   // [split][r(4)][x(34)][slot(16)][e(8)], slot = cl^(x&15)
    float* P = (float*)smem;   // [split][row(128) = rowl*64+ocl][stride 36][x(32)]

    const int mb = blockIdx.x;
    const int b = mb >> 4;
    const int h0 = (mb & 15) * 2;
    const int t = threadIdx.x;
    const int wave = t >> 6;
    const int lane = t & 63;
    const int l15 = lane & 15;
    const int q = lane >> 4;
    const int split = wave & 3;          // 4 splits
    const int hw = wave >> 2;            // oc-half (0..1)
    const int n0 = hw * 32;

    // ---- B pipeline prologue: issue steps 0..3 (overlaps staging VALU) ----
    // Step ts addr = bbase + ts*2048 shorts (4 KB per ts in the W3 layout).
    const short* bbase = W3 + (size_t)split * 73728 + (size_t)hw * 1024 + lane * 8;
    short8 pb0[4], pb1[4];
#pragma unroll
    for (int g = 0; g < 4; ++g)
        B_ISSUE(pb0[g], pb1[g], bbase + g * 2048);

    // ---- stage A: closed-form uniform cubic B-spline bases -> bf16 LDS ----
    for (int u = t; u < 4 * 34 * CINC; u += 512) {    // 8704 items, 17 iters
        int x34 = u % 34;
        int rc = u / 34;                 // 0..255
        int c6 = rc & 63;                // cin 0..63
        int rr = rc >> 6;
        int sp = c6 >> 4;                // which split's tile
        int cl = c6 & 15;
        int y = h0 + rr;
        float v = 0.0f;
        if (y >= 1 && y <= HH && x34 >= 1 && x34 <= WW)
            v = xin[((b * CINC + c6) * HH + (y - 1)) * WW + (x34 - 1)];
        float sv = fmaf(v, 2.5f, 5.5f);               // (v + 2.2) / 0.4
        float cf = floorf(sv);
        int c = (int)cf;
        float f = sv - cf;
        float f2 = f * f, f3 = f2 * f;
        float omf = 1.0f - f;
        float w0 = f3 * (1.0f / 6.0f);
        float w1 = (1.0f + 3.0f * f + 3.0f * f2 - 3.0f * f3) * (1.0f / 6.0f);
        float w2 = (4.0f - 6.0f * f2 + 3.0f * f3) * (1.0f / 6.0f);
        float w3 = (omf * omf * omf) * (1.0f / 6.0f);
        short o8[8];
#pragma unroll
        for (int j = 0; j < 8; ++j) {
            float bj = (j == c) ? w0 : (j == c - 1) ? w1 : (j == c - 2) ? w2
                       : (j == c - 3) ? w3 : 0.0f;
            o8[j] = (short)f2bf(bj);
        }
        *(int4*)&A[sp * 17408 + (rr * 34 + x34) * 128 + ((cl ^ (x34 & 15)) * 8)] =
            *(const int4*)o8;
    }
    __syncthreads();

    floatx4 acc[2][2][2];                // [row][xhalf][nt]
#pragma unroll
    for (int rl = 0; rl < 2; ++rl)
#pragma unroll
        for (int xh = 0; xh < 2; ++xh)
#pragma unroll
            for (int nt = 0; nt < 2; ++nt) acc[rl][xh][nt] = (floatx4)0.f;

    const int abase = split * 17408;

#define DO_STEP(B0, B1)                                                         \
    _Pragma("unroll")                                                           \
    for (int rl = 0; rl < 2; ++rl) {                                            \
        _Pragma("unroll")                                                       \
        for (int xh = 0; xh < 2; ++xh) {                                        \
            const int xi = xh * 16 + l15 + kw;                                  \
            short8 aF = *(const short8*)&A[abase + ((rl + kh) * 34 + xi) * 128 +\
                                           (((s * 4 + q) ^ (xi & 15)) * 8)];    \
            acc[rl][xh][0] = __builtin_amdgcn_mfma_f32_16x16x32_bf16(aF, B0, acc[rl][xh][0], 0, 0, 0); \
            acc[rl][xh][1] = __builtin_amdgcn_mfma_f32_16x16x32_bf16(aF, B1, acc[rl][xh][1], 0, 0, 0); \
        }                                                                       \
    }

    // ---- main loop: 36 steps = 9 taps x 4 k-quarters; consume-then-reissue ----
#pragma unroll
    for (int ts = 0; ts < 36; ++ts) {
        const int tap = ts >> 2, s = ts & 3;
        const int kh = tap / 3, kw = tap % 3;
        if (ts < 32)      { VM_WAIT(6, pb0[s], pb1[s]); }
        else if (ts == 32){ VM_WAIT(6, pb0[0], pb1[0]); }
        else if (ts == 33){ VM_WAIT(4, pb0[1], pb1[1]); }
        else if (ts == 34){ VM_WAIT(2, pb0[2], pb1[2]); }
        else              { VM_WAIT(0, pb0[3], pb1[3]); }
        DO_STEP(pb0[s], pb1[s])
        if (ts < 32) {                    // reissue AFTER the MFMAs read pb[s]
            B_ISSUE(pb0[s], pb1[s], bbase + (ts + 4) * 2048);
        }
    }
#undef DO_STEP

    // ---- epilogue: cross-split reduce via LDS, then direct out write ----
    __syncthreads();   // all A reads done; safe to alias with P
#pragma unroll
    for (int rl = 0; rl < 2; ++rl) {
#pragma unroll
        for (int xh = 0; xh < 2; ++xh) {
#pragma unroll
            for (int nt = 0; nt < 2; ++nt) {
                const int row = rl * 64 + n0 + nt * 16 + l15;   // 0..127
                *(floatx4*)(P + split * 4608 + row * 36 + xh * 16 + q * 4) =
                    acc[rl][xh][nt];
            }
        }
    }
    __syncthreads();
    for (int it = t; it < 1024; it += 512) {
        const int x4 = (it & 7) * 4;       // 0..28
        const int row = it >> 3;           // 0..127 = rowl*64 + ocl
        const int ocl = row & 63;
        const int hh = h0 + (row >> 6);
        const int po = row * 36 + x4;
        floatx4 v = *(const floatx4*)(P + po)
                  + *(const floatx4*)(P + 4608 + po)
                  + *(const floatx4*)(P + 2 * 4608 + po)
                  + *(const floatx4*)(P + 3 * 4608 + po);
        *(floatx4*)(out + (((size_t)b * COUT + ocl) * HH + hh) * WW + x4) = v;
    }
}

extern "C" void kernel_launch(void* const* d_in, const int* in_sizes, int n_in,
                              void* d_out, int out_size, void* d_ws, size_t ws_size,
                              hipStream_t stream) {
    const float* x  = (const float*)d_in[0];
    const float* sw = (const float*)d_in[1];
    const float* sc = (const float*)d_in[2];
    float* out = (float*)d_out;
    short* W3 = (short*)d_ws;                           // 294,912 bf16 = 576 KB

    wt_kernel<<<(294912 + 255) / 256, 256, 0, stream>>>(sw, sc, W3);
    conv_kernel<<<256, 512, 0, stream>>>(x, W3, out);
}